// Round 2
// baseline (666.424 us; speedup 1.0000x reference)
//
#include <hip/hip_runtime.h>
#include <math.h>

typedef __bf16 bf16;
typedef bf16 bf16x4 __attribute__((ext_vector_type(4)));
typedef bf16 bf16x8 __attribute__((ext_vector_type(8)));
typedef float f32x4 __attribute__((ext_vector_type(4)));

#define T_TOK   1024
#define H_DIM   2048
#define I_DIM   1024
#define E_NUM   16
#define NPAIR_R 4096
#define NPAIR   5120

// async global->LDS, 16B per lane (dest = wave-uniform base + lane*16, linear)
typedef __attribute__((address_space(3))) unsigned int lds_uint;
typedef __attribute__((address_space(1))) const unsigned int gbl_uint;
__device__ __forceinline__ void gld16(const void* g, void* l) {
  __builtin_amdgcn_global_load_lds((gbl_uint*)g, (lds_uint*)l, 16, 0, 0);
}

// ---------------- router (+ fused x->bf16 conversion, + out zeroing) ----------------
__global__ __launch_bounds__(256) void router_kernel(
    const float* __restrict__ x, const float* __restrict__ gate_w,
    const float* __restrict__ e_bias, bf16* __restrict__ xb,
    float* __restrict__ out,
    int* __restrict__ topk_ids, float* __restrict__ topk_w,
    int* __restrict__ counts)
{
  int t = blockIdx.x;
  int tid = threadIdx.x;
  float acc[16];
#pragma unroll
  for (int e = 0; e < 16; ++e) acc[e] = 0.f;
  const float* xr = x + (size_t)t * H_DIM;
  bf16* xbr = xb + (size_t)t * H_DIM;
  float* outr = out + (size_t)t * H_DIM;
  for (int h = tid; h < H_DIM; h += 256) {
    float xv = xr[h];
    xbr[h] = (bf16)xv;   // fused conversion for the GEMM A operand
    outr[h] = 0.f;       // fused out zeroing (replaces hipMemsetAsync)
#pragma unroll
    for (int e = 0; e < 16; ++e) acc[e] += xv * gate_w[e * H_DIM + h];
  }
#pragma unroll
  for (int e = 0; e < 16; ++e) {
#pragma unroll
    for (int off = 32; off >= 1; off >>= 1)
      acc[e] += __shfl_down(acc[e], off, 64);
  }
  __shared__ float red[4][16];
  int lane = tid & 63, wave = tid >> 6;
  if (lane == 0) {
#pragma unroll
    for (int e = 0; e < 16; ++e) red[wave][e] = acc[e];
  }
  __syncthreads();
  if (tid == 0) {
    float scores[16], sb[16];
    for (int e = 0; e < 16; ++e) {
      float l = red[0][e] + red[1][e] + red[2][e] + red[3][e];
      float s = 1.f / (1.f + expf(-l));
      scores[e] = s;
      sb[e] = s + e_bias[e];
    }
    float gs[4];
    for (int g = 0; g < 4; ++g) {
      float b1 = -1e30f, b2 = -1e30f;
      for (int j = 0; j < 4; ++j) {
        float v = sb[g * 4 + j];
        if (v > b1) { b2 = b1; b1 = v; }
        else if (v > b2) b2 = v;
      }
      gs[g] = b1 + b2;
    }
    int g1 = 0; float bv = gs[0];
    for (int g = 1; g < 4; ++g) if (gs[g] > bv) { bv = gs[g]; g1 = g; }
    int g2 = -1; float bv2 = -1e30f;
    for (int g = 0; g < 4; ++g) if (g != g1 && gs[g] > bv2) { bv2 = gs[g]; g2 = g; }
    float tmp[16];
    for (int e = 0; e < 16; ++e) {
      int grp = e >> 2;
      tmp[e] = (grp == g1 || grp == g2) ? sb[e] : 0.0f;
    }
    bool used[16] = {false};
    int ids[4]; float wv[4]; float wsum = 0.f;
    for (int k = 0; k < 4; ++k) {
      int bi = 0; float bvv = -1e30f;
      for (int i = 0; i < 16; ++i)
        if (!used[i] && tmp[i] > bvv) { bvv = tmp[i]; bi = i; }
      used[bi] = true;
      ids[k] = bi; wv[k] = scores[bi]; wsum += scores[bi];
    }
    float inv = 1.f / wsum;
    for (int k = 0; k < 4; ++k) {
      topk_ids[t * 4 + k] = ids[k];
      topk_w[t * 4 + k] = wv[k] * inv;
      atomicAdd(&counts[ids[k]], 1);
    }
  }
}

// ---------------- offsets + scatter fused (single block, LDS cursors) ----------------
__global__ __launch_bounds__(1024) void build_pairs_kernel(
    const int* __restrict__ topk_ids, const float* __restrict__ topk_w,
    const int* __restrict__ counts, int* __restrict__ off,
    int* __restrict__ pair_token, float* __restrict__ pair_scale)
{
  __shared__ int s_off[17];
  __shared__ int s_cur[16];
  int tid = threadIdx.x;
  if (tid == 0) {
    int s = 0;
    for (int e = 0; e < 16; ++e) { s_off[e] = s; off[e] = s; s += counts[e]; }
    s_off[16] = s; off[16] = s;
  }
  if (tid < 16) s_cur[tid] = 0;
  __syncthreads();
  for (int i = tid; i < NPAIR; i += 1024) {
    if (i < NPAIR_R) {
      int e = topk_ids[i];
      int pos = atomicAdd(&s_cur[e], 1);
      int idx = s_off[e] + pos;
      pair_token[idx] = i >> 2;
      pair_scale[idx] = 2.5f * topk_w[i];
    } else {
      pair_token[i] = i - NPAIR_R;
      pair_scale[i] = 1.0f;
    }
  }
}

// ======================= gate_up GEMM, depth-2 pipeline, fused SiLU =======================
// Block tile: 128 pairs x (64 gate + 64 up cols), BK=32, 3 LDS buffers.
// Per iter: issue stage(t+2) -> s_waitcnt vmcnt(12) (tiles t+1,t+2 stay in flight
// across the barriers; never drain to 0 in-loop) -> barrier -> frags+MFMA -> barrier.
__global__ __launch_bounds__(256, 2) void gateup_kernel(
    const bf16* __restrict__ xb, const float* __restrict__ w_gu,
    const float* __restrict__ s_wgu,
    const int* __restrict__ off, const int* __restrict__ pair_token,
    bf16* __restrict__ a_buf)
{
  const int nt = blockIdx.x;   // 0..15 over I in 64-col chunks
  const int mt = blockIdx.y;   // 0..7
  const int e  = blockIdx.z;   // 0..16 (16 = shared)
  const int poff = (e < 16) ? off[e]     : NPAIR_R;
  const int pend = (e < 16) ? off[e + 1] : NPAIR;
  const int cnt  = pend - poff;
  if (mt * 128 >= cnt) return;
  const float* __restrict__ B = (e < 16) ? (w_gu + (size_t)e * 2 * I_DIM * H_DIM) : s_wgu;

  __shared__ __align__(16) bf16  As[3 * 4096];   // 3 x 8 KB
  __shared__ __align__(16) float Bs[3 * 4096];   // 3 x 16 KB

  const int tid = threadIdx.x;
  const int lane = tid & 63;
  const int wave = tid >> 6;
  const int wm = wave >> 1, wn = wave & 1;
  const int c0 = lane >> 4;
  const int fr = lane & 15;

  const bf16* aptr[2];
#pragma unroll
  for (int s = 0; s < 2; ++s) {
    int idx = s * 256 + tid;
    int ar = idx >> 2, ach = idx & 3;
    int sch = ach ^ ((ar >> 1) & 3);
    int p = poff + mt * 128 + ar;            // < NPAIR always
    aptr[s] = xb + (size_t)pair_token[p] * H_DIM + sch * 8;
  }
  const float* bptr[4];
#pragma unroll
  for (int s = 0; s < 4; ++s) {
    int idx = s * 256 + tid;
    int br = idx >> 3, bch = idx & 7;
    int sch = bch ^ (br & 7);
    int rg = nt * 64 + br + (br >= 64 ? 960 : 0);   // gate rows / up rows
    bptr[s] = B + (size_t)rg * H_DIM + sch * 4;
  }
  int a_off[4];
#pragma unroll
  for (int mi = 0; mi < 4; ++mi) {
    int ar = wm * 64 + mi * 16 + fr;
    a_off[mi] = ar * 64 + ((c0 ^ ((ar >> 1) & 3)) << 4);
  }
  int b_off[4];
#pragma unroll
  for (int ni = 0; ni < 4; ++ni) {
    int br = wn * 32 + (ni & 1) * 16 + fr + (ni >> 1) * 64;
    b_off[ni] = br * 128 + (((2 * c0) ^ (br & 7)) << 4);
  }

  f32x4 acc[4][4];
  f32x4 zz = {0.f, 0.f, 0.f, 0.f};
#pragma unroll
  for (int mi = 0; mi < 4; ++mi)
#pragma unroll
    for (int ni = 0; ni < 4; ++ni) acc[mi][ni] = zz;

  const int ldso = tid * 16;
  auto stage = [&](int k0, int b) {
#pragma unroll
    for (int s = 0; s < 2; ++s)
      gld16(aptr[s] + k0, (char*)As + b * 8192 + s * 4096 + ldso);
#pragma unroll
    for (int s = 0; s < 4; ++s)
      gld16(bptr[s] + k0, (char*)Bs + b * 16384 + s * 4096 + ldso);
  };
  auto compute = [&](int b) {
    const char* Ab = (const char*)As + b * 8192;
    const char* Bb = (const char*)Bs + b * 16384;
    bf16x8 af[4], bv[4];
#pragma unroll
    for (int mi = 0; mi < 4; ++mi)
      af[mi] = *(const bf16x8*)(Ab + a_off[mi]);
#pragma unroll
    for (int ni = 0; ni < 4; ++ni) {
      f32x4 x0 = *(const f32x4*)(Bb + b_off[ni]);
      f32x4 x1 = *(const f32x4*)(Bb + (b_off[ni] ^ 16));
      bf16x8 t;
      t[0] = (bf16)x0[0]; t[1] = (bf16)x0[1]; t[2] = (bf16)x0[2]; t[3] = (bf16)x0[3];
      t[4] = (bf16)x1[0]; t[5] = (bf16)x1[1]; t[6] = (bf16)x1[2]; t[7] = (bf16)x1[3];
      bv[ni] = t;
    }
#pragma unroll
    for (int mi = 0; mi < 4; ++mi)
#pragma unroll
      for (int ni = 0; ni < 4; ++ni)
        acc[mi][ni] = __builtin_amdgcn_mfma_f32_16x16x32_bf16(af[mi], bv[ni], acc[mi][ni], 0, 0, 0);
  };

  const int NT = H_DIM / 32;   // 64
  stage(0, 0);
  stage(32, 1);
  int ca = 0, cb = 1, cc = 2;
  for (int t = 0; t + 2 < NT; ++t) {
    stage((t + 2) * 32, cc);
    asm volatile("s_waitcnt vmcnt(12)" ::: "memory");
    __builtin_amdgcn_s_barrier();
    compute(ca);
    asm volatile("" ::: "memory");
    __builtin_amdgcn_s_barrier();
    int tmp = ca; ca = cb; cb = cc; cc = tmp;
  }
  asm volatile("s_waitcnt vmcnt(6)" ::: "memory");
  __builtin_amdgcn_s_barrier();
  compute(ca);
  asm volatile("s_waitcnt vmcnt(0)" ::: "memory");
  __builtin_amdgcn_s_barrier();
  compute(cb);

  // epilogue: silu(gate)*up -> a_buf (bf16); gate = ni{0,1}, up = ni{2,3}
#pragma unroll
  for (int mi = 0; mi < 4; ++mi) {
#pragma unroll
    for (int reg = 0; reg < 4; ++reg) {
      int r = wm * 64 + mi * 16 + c0 * 4 + reg;
      int rl = mt * 128 + r;
      if (rl < cnt) {
        size_t p = (size_t)(poff + rl);
        bf16* orow = a_buf + p * I_DIM + nt * 64 + wn * 32 + fr;
#pragma unroll
        for (int ni = 0; ni < 2; ++ni) {
          float g = acc[mi][ni][reg];
          float u = acc[mi][ni + 2][reg];
          float sg = g / (1.f + expf(-g));
          orow[ni * 16] = (bf16)(sg * u);
        }
      }
    }
  }
}

// ======================= down GEMM, depth-2 pipeline, atomic scatter =======================
__global__ __launch_bounds__(256, 2) void down_kernel(
    const bf16* __restrict__ a_buf, const float* __restrict__ w_dn,
    const float* __restrict__ s_wdn,
    const int* __restrict__ off, const int* __restrict__ pair_token,
    const float* __restrict__ pair_scale, float* __restrict__ out)
{
  const int nt = blockIdx.x;   // 0..15 over H in 128-col chunks
  const int mt = blockIdx.y;   // 0..7
  const int e  = blockIdx.z;   // 0..16
  const int poff = (e < 16) ? off[e]     : NPAIR_R;
  const int pend = (e < 16) ? off[e + 1] : NPAIR;
  const int cnt  = pend - poff;
  if (mt * 128 >= cnt) return;
  const float* __restrict__ B = (e < 16) ? (w_dn + (size_t)e * H_DIM * I_DIM) : s_wdn;

  __shared__ __align__(16) bf16  As[3 * 4096];
  __shared__ __align__(16) float Bs[3 * 4096];

  const int tid = threadIdx.x;
  const int lane = tid & 63;
  const int wave = tid >> 6;
  const int wm = wave >> 1, wn = wave & 1;
  const int c0 = lane >> 4;
  const int fr = lane & 15;

  const bf16* aptr[2];
#pragma unroll
  for (int s = 0; s < 2; ++s) {
    int idx = s * 256 + tid;
    int ar = idx >> 2, ach = idx & 3;
    int sch = ach ^ ((ar >> 1) & 3);
    int p = poff + mt * 128 + ar;            // < NPAIR always
    aptr[s] = a_buf + (size_t)p * I_DIM + sch * 8;
  }
  const float* bptr[4];
#pragma unroll
  for (int s = 0; s < 4; ++s) {
    int idx = s * 256 + tid;
    int br = idx >> 3, bch = idx & 7;
    int sch = bch ^ (br & 7);
    bptr[s] = B + (size_t)(nt * 128 + br) * I_DIM + sch * 4;
  }
  int a_off[4];
#pragma unroll
  for (int mi = 0; mi < 4; ++mi) {
    int ar = wm * 64 + mi * 16 + fr;
    a_off[mi] = ar * 64 + ((c0 ^ ((ar >> 1) & 3)) << 4);
  }
  int b_off[4];
#pragma unroll
  for (int ni = 0; ni < 4; ++ni) {
    int br = wn * 64 + ni * 16 + fr;
    b_off[ni] = br * 128 + (((2 * c0) ^ (br & 7)) << 4);
  }

  f32x4 acc[4][4];
  f32x4 zz = {0.f, 0.f, 0.f, 0.f};
#pragma unroll
  for (int mi = 0; mi < 4; ++mi)
#pragma unroll
    for (int ni = 0; ni < 4; ++ni) acc[mi][ni] = zz;

  const int ldso = tid * 16;
  auto stage = [&](int k0, int b) {
#pragma unroll
    for (int s = 0; s < 2; ++s)
      gld16(aptr[s] + k0, (char*)As + b * 8192 + s * 4096 + ldso);
#pragma unroll
    for (int s = 0; s < 4; ++s)
      gld16(bptr[s] + k0, (char*)Bs + b * 16384 + s * 4096 + ldso);
  };
  auto compute = [&](int b) {
    const char* Ab = (const char*)As + b * 8192;
    const char* Bb = (const char*)Bs + b * 16384;
    bf16x8 af[4], bv[4];
#pragma unroll
    for (int mi = 0; mi < 4; ++mi)
      af[mi] = *(const bf16x8*)(Ab + a_off[mi]);
#pragma unroll
    for (int ni = 0; ni < 4; ++ni) {
      f32x4 x0 = *(const f32x4*)(Bb + b_off[ni]);
      f32x4 x1 = *(const f32x4*)(Bb + (b_off[ni] ^ 16));
      bf16x8 t;
      t[0] = (bf16)x0[0]; t[1] = (bf16)x0[1]; t[2] = (bf16)x0[2]; t[3] = (bf16)x0[3];
      t[4] = (bf16)x1[0]; t[5] = (bf16)x1[1]; t[6] = (bf16)x1[2]; t[7] = (bf16)x1[3];
      bv[ni] = t;
    }
#pragma unroll
    for (int mi = 0; mi < 4; ++mi)
#pragma unroll
      for (int ni = 0; ni < 4; ++ni)
        acc[mi][ni] = __builtin_amdgcn_mfma_f32_16x16x32_bf16(af[mi], bv[ni], acc[mi][ni], 0, 0, 0);
  };

  const int NT = I_DIM / 32;   // 32
  stage(0, 0);
  stage(32, 1);
  int ca = 0, cb = 1, cc = 2;
  for (int t = 0; t + 2 < NT; ++t) {
    stage((t + 2) * 32, cc);
    asm volatile("s_waitcnt vmcnt(12)" ::: "memory");
    __builtin_amdgcn_s_barrier();
    compute(ca);
    asm volatile("" ::: "memory");
    __builtin_amdgcn_s_barrier();
    int tmp = ca; ca = cb; cb = cc; cc = tmp;
  }
  asm volatile("s_waitcnt vmcnt(6)" ::: "memory");
  __builtin_amdgcn_s_barrier();
  compute(ca);
  asm volatile("s_waitcnt vmcnt(0)" ::: "memory");
  __builtin_amdgcn_s_barrier();
  compute(cb);

  const int colb = nt * 128 + wn * 64;
#pragma unroll
  for (int mi = 0; mi < 4; ++mi) {
#pragma unroll
    for (int reg = 0; reg < 4; ++reg) {
      int r = wm * 64 + mi * 16 + c0 * 4 + reg;
      int rl = mt * 128 + r;
      if (rl < cnt) {
        int p = poff + rl;
        int tok = pair_token[p];
        float sc = pair_scale[p];
        float* orow = out + (size_t)tok * H_DIM + colb + fr;
#pragma unroll
        for (int ni = 0; ni < 4; ++ni)
          atomicAdd(&orow[ni * 16], acc[mi][ni][reg] * sc);
      }
    }
  }
}

// ---------------- launch ----------------
extern "C" void kernel_launch(void* const* d_in, const int* in_sizes, int n_in,
                              void* d_out, int out_size, void* d_ws, size_t ws_size,
                              hipStream_t stream)
{
  const float* x     = (const float*)d_in[0];
  const float* gatew = (const float*)d_in[1];
  const float* ebias = (const float*)d_in[2];
  const float* w_gu  = (const float*)d_in[3];
  const float* w_dn  = (const float*)d_in[4];
  const float* s_wgu = (const float*)d_in[5];
  const float* s_wdn = (const float*)d_in[6];
  float* out = (float*)d_out;

  char* ws = (char*)d_ws;
  int*   off        = (int*)(ws + 0);        // 32 ints
  int*   counts     = (int*)(ws + 128);      // 16 ints
  int*   topk_ids   = (int*)(ws + 256);      // 4096 ints
  float* topk_w     = (float*)(ws + 16640);  // 4096 floats
  int*   pair_token = (int*)(ws + 33024);    // 5120 ints
  float* pair_scale = (float*)(ws + 53504);  // 5120 floats
  bf16*  x_bf16     = (bf16*)(ws + 73984);   // 1024*2048 bf16 = 4,194,304 B
  bf16*  a_buf      = (bf16*)(ws + 73984 + 4194304);  // 5120*1024 bf16

  hipMemsetAsync(ws + 128, 0, 64, stream);  // counts

  router_kernel<<<T_TOK, 256, 0, stream>>>(x, gatew, ebias, x_bf16, out,
                                           topk_ids, topk_w, counts);
  build_pairs_kernel<<<1, 1024, 0, stream>>>(topk_ids, topk_w, counts, off,
                                             pair_token, pair_scale);
  dim3 g1(16, 8, 17);
  gateup_kernel<<<g1, 256, 0, stream>>>(x_bf16, w_gu, s_wgu, off, pair_token, a_buf);
  dim3 g2(16, 8, 17);
  down_kernel<<<g2, 256, 0, stream>>>(a_buf, w_dn, s_wdn, off, pair_token, pair_scale, out);
}